// Round 6
// baseline (853.953 us; speedup 1.0000x reference)
//
#include <hip/hip_runtime.h>
#include <hip/hip_bf16.h>

// Problem: B=2, S=2048, HID=1024, NH=16, HD=64. fp32 in/out (per reference).
// d_out = [out (2*2048*1024) | attn (2*16*2048*2048)] fp32.
// NOTE: requires ws_size >= 71.3 MB (7*NQ + 6*NW bf16 elems).
#define BB   2
#define SS   2048
#define HID  1024
#define NH   16
#define HD   64
#define NEGS -30000.0f

typedef __bf16 bf16x8 __attribute__((ext_vector_type(8)));
typedef __bf16 bf16x4 __attribute__((ext_vector_type(4)));
typedef float  f32x4  __attribute__((ext_vector_type(4)));

static __device__ __forceinline__ f32x4 mfma_bf16(bf16x8 a, bf16x8 b, f32x4 c) {
    return __builtin_amdgcn_mfma_f32_16x16x32_bf16(a, b, c, 0, 0, 0);
}

static __device__ __forceinline__ void split_bf16(float f, __bf16* hp, __bf16* lp) {
    __bf16 h = (__bf16)f;
    *hp = h;
    *lp = (__bf16)(f - (float)h);
}

static __device__ __forceinline__ float clampf(float v, float lo, float hi) {
    return fminf(fmaxf(v, lo), hi);   // also scrubs NaN -> lo
}

// async global->LDS, 16B per lane; dest must be wave-uniform base (+ lane*16 by HW)
static __device__ __forceinline__ void gll16(const __bf16* g, __bf16* l) {
    __builtin_amdgcn_global_load_lds((const void*)g, (void*)l, 16, 0, 0);
}

// barrier that drains only LDS counters (keeps global_load_lds prefetch in flight)
static __device__ __forceinline__ void barrier_lds() {
    asm volatile("s_waitcnt lgkmcnt(0)" ::: "memory");
    __builtin_amdgcn_sched_barrier(0);
    __builtin_amdgcn_s_barrier();
    __builtin_amdgcn_sched_barrier(0);
}

// counted-vmcnt barriers: wait the oldest staged tile, keep newer prefetch
// (and store acks) in flight.
static __device__ __forceinline__ void barrier_vm0() {
    asm volatile("s_waitcnt vmcnt(0) lgkmcnt(0)" ::: "memory");
    __builtin_amdgcn_sched_barrier(0);
    __builtin_amdgcn_s_barrier();
    __builtin_amdgcn_sched_barrier(0);
}
static __device__ __forceinline__ void barrier_vm2() {
    asm volatile("s_waitcnt vmcnt(2) lgkmcnt(0)" ::: "memory");
    __builtin_amdgcn_sched_barrier(0);
    __builtin_amdgcn_s_barrier();
    __builtin_amdgcn_sched_barrier(0);
}
static __device__ __forceinline__ void barrier_vm4() {
    asm volatile("s_waitcnt vmcnt(4) lgkmcnt(0)" ::: "memory");
    __builtin_amdgcn_sched_barrier(0);
    __builtin_amdgcn_s_barrier();
    __builtin_amdgcn_sched_barrier(0);
}

// ---------------------------------------------------------------------------
// K0: one-time hi/lo bf16 pre-split of x and the weights. Tight 1D grid.
// Wq is pre-scaled by 8 (exact: power-of-2), so qkv folds the score scale.
// ---------------------------------------------------------------------------
__global__ __launch_bounds__(256) void split_kernel(
    const float* __restrict__ x,
    const float* __restrict__ Wq, const float* __restrict__ Wk,
    const float* __restrict__ Wv, const float* __restrict__ Wo,
    __bf16* __restrict__ xh, __bf16* __restrict__ xl,
    __bf16* __restrict__ wqh, __bf16* __restrict__ wql,
    __bf16* __restrict__ wkh, __bf16* __restrict__ wkl,
    __bf16* __restrict__ wvh, __bf16* __restrict__ woh)
{
    const int bid = blockIdx.x;
    if (bid < 4096) {                      // x: 4096*256*4 == BB*SS*HID exactly
        const int i4 = bid * 256 + threadIdx.x;
        const float4 v = ((const float4*)x)[i4];
        const float* p = (const float*)&v;
        bf16x4 h4, l4v;
#pragma unroll
        for (int j = 0; j < 4; j++) { __bf16 hh, ll; split_bf16(p[j], &hh, &ll); h4[j] = hh; l4v[j] = ll; }
        *(bf16x4*)&xh[(size_t)i4 * 4] = h4;
        *(bf16x4*)&xl[(size_t)i4 * 4] = l4v;
        return;
    }
    const int wb = bid - 4096;             // 4 x 1024 blocks, 1024*256*4 == HID*HID
    const int which = (wb >> 10) + 1;
    const int i4 = (wb & 1023) * 256 + threadIdx.x;
    const float* src = which == 1 ? Wq : which == 2 ? Wk : which == 3 ? Wv : Wo;
    const float sc = (which == 1) ? 8.0f : 1.0f;
    const float4 v = ((const float4*)src)[i4];
    const float* p = (const float*)&v;
    bf16x4 h4, l4v;
#pragma unroll
    for (int j = 0; j < 4; j++) { __bf16 hh, ll; split_bf16(p[j] * sc, &hh, &ll); h4[j] = hh; l4v[j] = ll; }
    if (which == 1)      { *(bf16x4*)&wqh[(size_t)i4 * 4] = h4; *(bf16x4*)&wql[(size_t)i4 * 4] = l4v; }
    else if (which == 2) { *(bf16x4*)&wkh[(size_t)i4 * 4] = h4; *(bf16x4*)&wkl[(size_t)i4 * 4] = l4v; }
    else if (which == 3) { *(bf16x4*)&wvh[(size_t)i4 * 4] = h4; }
    else                 { *(bf16x4*)&woh[(size_t)i4 * 4] = h4; }
}

// ---------------------------------------------------------------------------
// K1: QKV projection, 128x128 tile, BK=32, gll staging, double-buffered LDS.
// Q/K: 3-chain MFMA (hi*hi + hi*lo + lo*hi), V: hi-only.  (unchanged from v5)
// ---------------------------------------------------------------------------
__global__ __launch_bounds__(256) void qkv_kernel(
    const __bf16* __restrict__ xh, const __bf16* __restrict__ xl,
    const __bf16* __restrict__ wqh, const __bf16* __restrict__ wql,
    const __bf16* __restrict__ wkh, const __bf16* __restrict__ wkl,
    const __bf16* __restrict__ wvh,
    const float* __restrict__ bq, const float* __restrict__ bk, const float* __restrict__ bv,
    __bf16* __restrict__ qh, __bf16* __restrict__ ql,
    __bf16* __restrict__ kh, __bf16* __restrict__ kl,
    __bf16* __restrict__ vt)
{
    // buffer set b at smem + b*16384: Ah=+0, Al=+4096, Bh=+8192, Bl=+12288
    __shared__ __align__(16) __bf16 smem[32768];   // 64KB -> 2 blocks/CU

    const int stream = blockIdx.x >> 3, ct = blockIdx.x & 7;
    const int t0 = blockIdx.y * 128, c0 = ct * 128;
    const bool qk = stream < 2;
    const __bf16* const Bhg = stream == 0 ? wqh : stream == 1 ? wkh : wvh;
    const __bf16* const Blg = stream == 0 ? wql : wkl;     // unused for V
    const float* const bias = stream == 0 ? bq : stream == 1 ? bk : bv;
    const float bscale = stream == 0 ? 8.0f : 1.0f;        // Wq pre-scaled: scale bias too

    const int tid = threadIdx.x, wave = tid >> 6, lane = tid & 63;
    const int l16 = lane & 15, quad = lane >> 4;
    const int wr = wave >> 1, wc = wave & 1;

    // staging map: 4 16B slots/row, slot-XOR swizzle by (row&3) on BOTH sides
    const int ar0 = tid >> 2,         as0 = (tid & 3) ^ (ar0 & 3);
    const int ar1 = (256 + tid) >> 2, as1 = ((256 + tid) & 3) ^ (ar1 & 3);
    const size_t aoff0 = (size_t)(t0 + ar0) * HID + as0 * 8;
    const size_t aoff1 = (size_t)(t0 + ar1) * HID + as1 * 8;
    const size_t boff0 = (size_t)(c0 + ar0) * HID + as0 * 8;
    const size_t boff1 = (size_t)(c0 + ar1) * HID + as1 * 8;
    const int ld0 = wave << 9, ld1 = (4 + wave) << 9;      // 1KB chunks per wave

#define QKV_STAGE(b_, k0_) do {                                   \
        __bf16* s_ = smem + (b_) * 16384;                         \
        gll16(xh + aoff0 + (k0_), s_ + ld0);                      \
        gll16(xh + aoff1 + (k0_), s_ + ld1);                      \
        gll16(Bhg + boff0 + (k0_), s_ + 8192 + ld0);              \
        gll16(Bhg + boff1 + (k0_), s_ + 8192 + ld1);              \
        if (qk) {                                                 \
            gll16(xl + aoff0 + (k0_), s_ + 4096 + ld0);           \
            gll16(xl + aoff1 + (k0_), s_ + 4096 + ld1);           \
            gll16(Blg + boff0 + (k0_), s_ + 12288 + ld0);         \
            gll16(Blg + boff1 + (k0_), s_ + 12288 + ld1);         \
        }                                                         \
    } while (0)

    const f32x4 zero4 = {0.f, 0.f, 0.f, 0.f};
    f32x4 acc[4][4];
#pragma unroll
    for (int i = 0; i < 4; i++)
#pragma unroll
        for (int j = 0; j < 4; j++) acc[i][j] = zero4;

    QKV_STAGE(0, 0);
    for (int k0 = 0; k0 < HID; k0 += 32) {
        const int cur = (k0 >> 5) & 1;
        __syncthreads();                 // buf[cur] landed; prev readers of buf[cur^1] done
        if (k0 + 32 < HID) QKV_STAGE(cur ^ 1, k0 + 32);
        __bf16* const s_ = smem + cur * 16384;

        bf16x8 aH[4], aL[4], bHf[4], bLf[4];
#pragma unroll
        for (int mf = 0; mf < 4; mf++) {
            const int row = wr * 64 + mf * 16 + l16;
            const int off = row * 32 + ((quad ^ (row & 3)) << 3);
            aH[mf] = *(const bf16x8*)(s_ + off);
            if (qk) aL[mf] = *(const bf16x8*)(s_ + 4096 + off);
        }
#pragma unroll
        for (int nf = 0; nf < 4; nf++) {
            const int row = wc * 64 + nf * 16 + l16;
            const int off = row * 32 + ((quad ^ (row & 3)) << 3);
            bHf[nf] = *(const bf16x8*)(s_ + 8192 + off);
            if (qk) bLf[nf] = *(const bf16x8*)(s_ + 12288 + off);
        }
        __builtin_amdgcn_s_setprio(1);
#pragma unroll
        for (int mf = 0; mf < 4; mf++)
#pragma unroll
            for (int nf = 0; nf < 4; nf++) {
                acc[mf][nf] = mfma_bf16(aH[mf], bHf[nf], acc[mf][nf]);
                if (qk) {
                    acc[mf][nf] = mfma_bf16(aH[mf], bLf[nf], acc[mf][nf]);
                    acc[mf][nf] = mfma_bf16(aL[mf], bHf[nf], acc[mf][nf]);
                }
            }
        __builtin_amdgcn_s_setprio(0);
    }
#undef QKV_STAGE

    const int bidx = t0 >> 11;           // batch (tile never crosses batch boundary)
    const int s0 = t0 & (SS - 1);

    if (qk) {
        // epilogue via LDS: [128][132] bf16, coalesced uint4 stores, hi then lo
        __bf16* const Es = smem;
        __bf16* const hi_arr = stream == 0 ? qh : kh;
        __bf16* const lo_arr = stream == 0 ? ql : kl;
#pragma unroll
        for (int pass = 0; pass < 2; pass++) {
            __syncthreads();             // prior smem readers (frags / pass-0 stores) done
#pragma unroll
            for (int nf = 0; nf < 4; nf++) {
                const int dcl = wc * 64 + nf * 16 + l16;
                const float bv_ = bias[c0 + dcl] * bscale;
#pragma unroll
                for (int mf = 0; mf < 4; mf++)
#pragma unroll
                    for (int r = 0; r < 4; r++) {
                        const int srl = wr * 64 + mf * 16 + quad * 4 + r;
                        const float v = clampf(acc[mf][nf][r] + bv_, -1e4f, 1e4f);
                        __bf16 hv, lv;
                        split_bf16(v, &hv, &lv);
                        Es[srl * 132 + dcl] = pass ? lv : hv;
                    }
            }
            __syncthreads();
            __bf16* const dst = pass ? lo_arr : hi_arr;
#pragma unroll
            for (int i = 0; i < 8; i++) {
                const int idx = tid + i * 256;           // 2048 16B chunks
                const int row = idx >> 4, c16 = idx & 15;
                const int hh = (c0 >> 6) + (c16 >> 3);
                const int dd = (c16 & 7) * 8;
                const size_t o = ((size_t)(bidx * NH + hh) * SS + (s0 + row)) * HD + dd;
                *(uint4*)&dst[o] = *(const uint4*)&Es[row * 132 + c16 * 8];
            }
        }
    } else {
        // V: each wave transposes its own 64x64 subtile through its own LDS region
        __syncthreads();                            // all frag reads of smem done
        __bf16* const Vts = smem + wave * 4608;     // [64][72]
#pragma unroll
        for (int nf = 0; nf < 4; nf++) {
            const int dloc = nf * 16 + l16;
            const float bv_ = bias[c0 + wc * 64 + dloc];
#pragma unroll
            for (int mf = 0; mf < 4; mf++)
#pragma unroll
                for (int r = 0; r < 4; r++)
                    Vts[dloc * 72 + mf * 16 + quad * 4 + r] =
                        (__bf16)clampf(acc[mf][nf][r] + bv_, -1e4f, 1e4f);
        }
        const int hh = (c0 + wc * 64) >> 6;
        const size_t vb = (size_t)(bidx * NH + hh) * HD * SS;
        const int sc0 = s0 + wr * 64;
#pragma unroll
        for (int j = 0; j < 8; j++) {               // same-wave readback: no barrier needed
            const int idx = j * 64 + lane;
            const int d = idx >> 3, c8 = idx & 7;
            *(uint4*)&vt[vb + (size_t)d * SS + sc0 + c8 * 8] =
                *(const uint4*)&Vts[d * 72 + c8 * 8];
        }
    }
}

// ---------------------------------------------------------------------------
// K2: causal attention, two-pass online softmax.
// v6: pass A triple-buffers K through the idle V buffers (prefetch depth 2,
// counted vmcnt(2) barriers -> newest prefetch never drained); s_setprio(1)
// around MFMA clusters; PV before attn store; attn + zero-fill stores
// nontemporal (keep K/V hot in L2). Math identical to v5.
// ---------------------------------------------------------------------------
__global__ __launch_bounds__(512, 4) void attn_kernel(
    const __bf16* __restrict__ qh, const __bf16* __restrict__ ql,
    const __bf16* __restrict__ kh, const __bf16* __restrict__ kl,
    const __bf16* __restrict__ vt,
    float* __restrict__ attn, __bf16* __restrict__ ctx)
{
    __shared__ __align__(16) __bf16 Kh0[4096], Kl0[4096], Kh1[4096], Kl1[4096];
    __shared__ __align__(16) __bf16 Vt0[4096], Vt1[4096];
    __shared__ __align__(16) __bf16 Ps[128][72];      // 66KB total

    const int bid  = blockIdx.x;           // [0,512)
    const int half = bid >> 8;             // 0: heavy qt 15..8, 1: light qt 0..7
    const int ii   = bid & 255;
    const int g    = ii & 7;               // XCD (round-robin)
    const int bh   = g + 8 * ((ii >> 3) & 3);   // 4 bh per XCD
    const int p    = ii >> 5;              // [0,8)
    const int qt   = half ? p : (15 - p);
    const int nj   = 2 * qt + 2;
    const int b    = bh >> 4, h = bh & 15;

    const int tid  = threadIdx.x;
    const int wave = tid >> 6, lane = tid & 63;
    const int l16  = lane & 15, quad = lane >> 4;

    // gll staging map (512 thr: one call covers a 64x128B tile)
    const int sr = tid >> 3, ssw = (tid & 7) ^ (sr & 7);
    const size_t kq = (size_t)sr * HD + ssw * 8;
    const size_t vq = (size_t)sr * SS + ssw * 8;
    const int ldw = wave << 9;

    const __bf16* const khp = kh + (size_t)bh * SS * HD;
    const __bf16* const klp = kl + (size_t)bh * SS * HD;
    const __bf16* const vtp = vt + (size_t)bh * HD * SS;

#define STAGE_K(j_, KH, KL) do {                                  \
        const __bf16* kg_ = khp + (size_t)(j_) * (64 * HD);       \
        const __bf16* lg_ = klp + (size_t)(j_) * (64 * HD);       \
        gll16(kg_ + kq, (KH) + ldw); gll16(lg_ + kq, (KL) + ldw); \
    } while (0)
#define STAGE_V(j_, VT) do {                                      \
        const __bf16* vg_ = vtp + (size_t)(j_) * 64;              \
        gll16(vg_ + vq, (VT) + ldw);                              \
    } while (0)

    const f32x4 zero4 = {0.f, 0.f, 0.f, 0.f};

    // Q fragments straight to registers (128B-row coalesced loads)
    bf16x8 aHq[2], aLq[2];
    {
        const size_t qrow = ((size_t)bh * SS + qt * 128 + wave * 16 + l16) * HD;
#pragma unroll
        for (int ks = 0; ks < 2; ks++) {
            aHq[ks] = *(const bf16x8*)&qh[qrow + ks * 32 + quad * 8];
            aLq[ks] = *(const bf16x8*)&ql[qrow + ks * 32 + quad * 8];
        }
    }

    float m4[4], l4[4];
#pragma unroll
    for (int r = 0; r < 4; r++) { m4[r] = NEGS; l4[r] = 0.f; }

    // ---- pass A: per-lane online max/sumexp; K triple-buffered (V bufs idle) ----
    STAGE_K(0, Kh0, Kl0);                   // nj >= 2 always
    STAGE_K(1, Kh1, Kl1);

    for (int j = 0; j < nj; j++) {
        const int bi = j % 3;
        // wait stage(j); stage(j+1)'s 2 glls (if issued) stay in flight
        if (j + 1 < nj) barrier_vm2(); else barrier_vm0();
        if (j + 2 < nj) {                   // prefetch depth 2
            const int st = bi == 0 ? 2 : bi - 1;
            __bf16* const KHs = st == 0 ? Kh0 : (st == 1 ? Kh1 : Vt0);
            __bf16* const KLs = st == 0 ? Kl0 : (st == 1 ? Kl1 : Vt1);
            STAGE_K(j + 2, KHs, KLs);
        }
        const __bf16* const Khc = bi == 0 ? Kh0 : (bi == 1 ? Kh1 : Vt0);
        const __bf16* const Klc = bi == 0 ? Kl0 : (bi == 1 ? Kl1 : Vt1);

        f32x4 sacc[4] = {zero4, zero4, zero4, zero4};
        __builtin_amdgcn_s_setprio(1);
#pragma unroll
        for (int ks = 0; ks < 2; ks++)
#pragma unroll
            for (int c = 0; c < 4; c++) {
                const int krow = c * 16 + l16;
                const int ko = krow * 64 + (((ks * 4 + quad) ^ (krow & 7)) << 3);
                const bf16x8 bH = *(const bf16x8*)(Khc + ko);
                const bf16x8 bL = *(const bf16x8*)(Klc + ko);
                sacc[c] = mfma_bf16(aHq[ks], bH, sacc[c]);
                sacc[c] = mfma_bf16(aHq[ks], bL, sacc[c]);
                sacc[c] = mfma_bf16(aLq[ks], bH, sacc[c]);
            }
        __builtin_amdgcn_s_setprio(0);
        if (j >= 2 * qt) {
            const int cb = j * 64, qr = qt * 128 + wave * 16 + quad * 4;
#pragma unroll
            for (int c = 0; c < 4; c++) {
                const int col = cb + c * 16 + l16;
#pragma unroll
                for (int r = 0; r < 4; r++)
                    if (col > qr + r) sacc[c][r] = NEGS;
            }
        }
#pragma unroll
        for (int r = 0; r < 4; r++) {       // lane-local online update
            const float mx = fmaxf(fmaxf(sacc[0][r], sacc[1][r]),
                                   fmaxf(sacc[2][r], sacc[3][r]));
            const float mn = fmaxf(m4[r], mx);
            l4[r] = l4[r] * __expf(m4[r] - mn)
                  + __expf(sacc[0][r] - mn) + __expf(sacc[1][r] - mn)
                  + __expf(sacc[2][r] - mn) + __expf(sacc[3][r] - mn);
            m4[r] = mn;
        }
    }

    // single cross-lane merge over 16-lane column groups
    float il[4];
#pragma unroll
    for (int r = 0; r < 4; r++) {
#pragma unroll
        for (int off = 1; off < 16; off <<= 1) {
            const float mo  = __shfl_xor(m4[r], off);
            const float lo_ = __shfl_xor(l4[r], off);
            const float mn  = fmaxf(m4[r], mo);
            l4[r] = l4[r] * __expf(m4[r] - mn) + lo_ * __expf(mo - mn);
            m4[r] = mn;
        }
        il[r] = (l4[r] > 0.f) ? (1.0f / l4[r]) : 0.f;
    }

    f32x4 cacc[4] = {zero4, zero4, zero4, zero4};

    __syncthreads();                        // pass-A buffer reads finished everywhere
    STAGE_K(0, Kh0, Kl0);
    STAGE_V(0, Vt0);

    // ---- pass B: attn write (fp32, NT) + ctx accumulate ----
    for (int j = 0; j < nj; j++) {
        if (j == 0) barrier_vm0();          // initial tile landed
        else        barrier_vm4();          // staged tile landed; store acks in flight
        if (j < nj - 1) {
            if (j & 1) { STAGE_K(j + 1, Kh0, Kl0); STAGE_V(j + 1, Vt0); }
            else       { STAGE_K(j + 1, Kh1, Kl1); STAGE_V(j + 1, Vt1); }
        }
        const __bf16* const Khc = (j & 1) ? Kh1 : Kh0;
        const __bf16* const Klc = (j & 1) ? Kl1 : Kl0;
        const __bf16* const Vtc = (j & 1) ? Vt1 : Vt0;

        f32x4 sacc[4] = {zero4, zero4, zero4, zero4};
        __builtin_amdgcn_s_setprio(1);
#pragma unroll
        for (int ks = 0; ks < 2; ks++)
#pragma unroll
            for (int c = 0; c < 4; c++) {
                const int krow = c * 16 + l16;
                const int ko = krow * 64 + (((ks * 4 + quad) ^ (krow & 7)) << 3);
                const bf16x8 bH = *(const bf16x8*)(Khc + ko);
                const bf16x8 bL = *(const bf16x8*)(Klc + ko);
                sacc[c] = mfma_bf16(aHq[ks], bH, sacc[c]);
                sacc[c] = mfma_bf16(aHq[ks], bL, sacc[c]);
                sacc[c] = mfma_bf16(aLq[ks], bH, sacc[c]);
            }
        __builtin_amdgcn_s_setprio(0);
        if (j >= 2 * qt) {
            const int cb = j * 64, qr = qt * 128 + wave * 16 + quad * 4;
#pragma unroll
            for (int c = 0; c < 4; c++) {
                const int col = cb + c * 16 + l16;
#pragma unroll
                for (int r = 0; r < 4; r++)
                    if (col > qr + r) sacc[c][r] = NEGS;
            }
        }
#pragma unroll
        for (int c = 0; c < 4; c++)
#pragma unroll
            for (int r = 0; r < 4; r++) {
                const float pv = clampf(__expf(sacc[c][r] - m4[r]) * il[r], 0.f, 1.f);
                Ps[wave * 16 + quad * 4 + r][c * 16 + l16] = (__bf16)pv;
            }
        barrier_lds();                      // Ps visible; gll prefetch NOT drained

        // ctx += P @ V (matrix pipe first, not queued behind store issue)
        __builtin_amdgcn_s_setprio(1);
#pragma unroll
        for (int ks = 0; ks < 2; ks++) {
            const bf16x8 ap = *(const bf16x8*)&Ps[wave * 16 + l16][ks * 32 + quad * 8];
#pragma unroll
            for (int dt = 0; dt < 4; dt++) {
                const int vrow = dt * 16 + l16;
                const int vo = vrow * 64 + (((ks * 4 + quad) ^ (vrow & 7)) << 3);
                cacc[dt] = mfma_bf16(ap, *(const bf16x8*)(Vtc + vo), cacc[dt]);
            }
        }
        __builtin_amdgcn_s_setprio(0);

        // coalesced fp32 attn store (nontemporal: never re-read, spare the L2)
#pragma unroll
        for (int i = 0; i < 2; i++) {
            const int idx = tid + i * 512;
            const int row = idx >> 3, c8 = idx & 7;
            const size_t o = ((size_t)bh * SS + qt * 128 + row) * SS + j * 64 + c8 * 8;
            __bf16 tmp[8];
            *(uint4*)tmp = *(const uint4*)&Ps[row][c8 * 8];
            f32x4 f0, f1;
            f0[0] = (float)tmp[0]; f0[1] = (float)tmp[1];
            f0[2] = (float)tmp[2]; f0[3] = (float)tmp[3];
            f1[0] = (float)tmp[4]; f1[1] = (float)tmp[5];
            f1[2] = (float)tmp[6]; f1[3] = (float)tmp[7];
            __builtin_nontemporal_store(f0, (f32x4*)&attn[o]);
            __builtin_nontemporal_store(f1, (f32x4*)&attn[o + 4]);
        }
    }

    // zero-fill upper-triangle tiles (fp32, NT)
    const f32x4 zf4 = {0.f, 0.f, 0.f, 0.f};
    for (int j = nj; j < SS / 64; j++) {
#pragma unroll
        for (int i = 0; i < 4; i++) {
            const int idx = tid + i * 512;          // [0,2048)
            const int row = idx >> 4, c4 = idx & 15;
            const size_t o = ((size_t)bh * SS + qt * 128 + row) * SS + j * 64 + c4 * 4;
            __builtin_nontemporal_store(zf4, (f32x4*)&attn[o]);
        }
    }

    // ctx epilogue via Ps: coalesced bf16 stores (re-read by out_kernel: cached)
    __syncthreads();                        // all Ps readers (attn store/PV) done
#pragma unroll
    for (int dt = 0; dt < 4; dt++) {
        const int d = dt * 16 + l16;
#pragma unroll
        for (int r = 0; r < 4; r++)
            Ps[wave * 16 + quad * 4 + r][d] =
                (__bf16)clampf(cacc[dt][r], -1e4f, 1e4f);
    }
    __syncthreads();
#pragma unroll
    for (int i = 0; i < 2; i++) {
        const int idx = tid + i * 512;              // 1024 chunks = 128 rows x 8
        const int row = idx >> 3, c8 = idx & 7;
        *(uint4*)&ctx[(size_t)(b * SS + qt * 128 + row) * HID + h * 64 + c8 * 8] =
            *(const uint4*)&Ps[row][c8 * 8];
    }
#undef STAGE_K
#undef STAGE_V
}

// ---------------------------------------------------------------------------
// K3: out = ctx @ Wo^T + bo   (ctx bf16, woh pre-split bf16-hi)
// v6: final stores nontemporal. 128x64 tile, grid (16,32), dbuf LDS.
// ---------------------------------------------------------------------------
__global__ __launch_bounds__(256) void out_kernel(
    const __bf16* __restrict__ ctx, const __bf16* __restrict__ woh,
    const float* __restrict__ bo, float* __restrict__ out)
{
    // buffer set b at smem + b*6144: As(128x32)=+0, Bs(64x32)=+4096
    __shared__ __align__(16) __bf16 smem[12288];   // 24KB

    const int o0 = blockIdx.x * 64;      // N-tile (output cols)
    const int t0 = blockIdx.y * 128;     // M-tile (rows)

    const int tid = threadIdx.x, wave = tid >> 6, lane = tid & 63;
    const int l16 = lane & 15, quad = lane >> 4;
    const int wr = wave >> 1, wc = wave & 1;   // 2x2 wave grid: 64 rows x 32 cols each

    // A staging: 128 rows, 2 glls/wave; B staging: 64 rows, 1 gll/wave
    const int ar0 = tid >> 2,         as0 = (tid & 3) ^ (ar0 & 3);
    const int ar1 = (256 + tid) >> 2, as1 = ((256 + tid) & 3) ^ (ar1 & 3);
    const size_t aoff0 = (size_t)(t0 + ar0) * HID + as0 * 8;
    const size_t aoff1 = (size_t)(t0 + ar1) * HID + as1 * 8;
    const size_t boff  = (size_t)(o0 + ar0) * HID + as0 * 8;   // ar0<64 covered by tid<256
    const int ld0 = wave << 9, ld1 = (4 + wave) << 9;

#define OUT_STAGE(b_, k0_) do {                                   \
        __bf16* s_ = smem + (b_) * 6144;                          \
        gll16(ctx + aoff0 + (k0_), s_ + ld0);                     \
        gll16(ctx + aoff1 + (k0_), s_ + ld1);                     \
        gll16(woh + boff + (k0_), s_ + 4096 + ld0);               \
    } while (0)

    const f32x4 zero4 = {0.f, 0.f, 0.f, 0.f};
    f32x4 acc[4][2];
#pragma unroll
    for (int i = 0; i < 4; i++)
#pragma unroll
        for (int j = 0; j < 2; j++) acc[i][j] = zero4;

    OUT_STAGE(0, 0);
    for (int k0 = 0; k0 < HID; k0 += 32) {
        const int cur = (k0 >> 5) & 1;
        __syncthreads();                 // buf[cur] landed; prev readers of buf[cur^1] done
        if (k0 + 32 < HID) OUT_STAGE(cur ^ 1, k0 + 32);
        __bf16* const s_ = smem + cur * 6144;

        bf16x8 aH[4], bHf[2];
#pragma unroll
        for (int mf = 0; mf < 4; mf++) {
            const int row = wr * 64 + mf * 16 + l16;
            aH[mf] = *(const bf16x8*)(s_ + row * 32 + ((quad ^ (row & 3)) << 3));
        }
#pragma unroll
        for (int nf = 0; nf < 2; nf++) {
            const int row = wc * 32 + nf * 16 + l16;
            bHf[nf] = *(const bf16x8*)(s_ + 4096 + row * 32 + ((quad ^ (row & 3)) << 3));
        }
        __builtin_amdgcn_s_setprio(1);
#pragma unroll
        for (int mf = 0; mf < 4; mf++)
#pragma unroll
            for (int nf = 0; nf < 2; nf++)
                acc[mf][nf] = mfma_bf16(aH[mf], bHf[nf], acc[mf][nf]);
        __builtin_amdgcn_s_setprio(0);
    }
#undef OUT_STAGE

#pragma unroll
    for (int nf = 0; nf < 2; nf++) {
        const int dcol = o0 + wc * 32 + nf * 16 + l16;
        const float bias = bo[dcol];
#pragma unroll
        for (int mf = 0; mf < 4; mf++)
#pragma unroll
            for (int r = 0; r < 4; r++) {
                const int t = t0 + wr * 64 + mf * 16 + quad * 4 + r;
                __builtin_nontemporal_store(clampf(acc[mf][nf][r] + bias, -1e4f, 1e4f),
                                            &out[(size_t)t * HID + dcol]);
            }
    }
}

extern "C" void kernel_launch(void* const* d_in, const int* in_sizes, int n_in,
                              void* d_out, int out_size, void* d_ws, size_t ws_size,
                              hipStream_t stream) {
    const float* x  = (const float*)d_in[0];
    const float* Wq = (const float*)d_in[1];
    const float* bq = (const float*)d_in[2];
    const float* Wk = (const float*)d_in[3];
    const float* bk = (const float*)d_in[4];
    const float* Wv = (const float*)d_in[5];
    const float* bv = (const float*)d_in[6];
    const float* Wo = (const float*)d_in[7];
    const float* bo = (const float*)d_in[8];

    float* out  = (float*)d_out;
    float* attn = out + (size_t)BB * SS * HID;

    const size_t NQ = (size_t)BB * NH * SS * HD;   // 4,194,304
    const size_t NW = (size_t)HID * HID;           // 1,048,576
    __bf16* ws  = (__bf16*)d_ws;
    __bf16* qh  = ws;
    __bf16* ql  = ws + NQ;
    __bf16* kh  = ws + 2 * NQ;
    __bf16* kl  = ws + 3 * NQ;
    __bf16* vt  = ws + 4 * NQ;
    __bf16* xh  = ws + 5 * NQ;     // dead after qkv -> reused as ctx
    __bf16* xl  = ws + 6 * NQ;
    __bf16* wqh = ws + 7 * NQ;
    __bf16* wql = wqh + NW;
    __bf16* wkh = wqh + 2 * NW;
    __bf16* wkl = wqh + 3 * NW;
    __bf16* wvh = wqh + 4 * NW;
    __bf16* woh = wqh + 5 * NW;    // total (7*NQ + 6*NW)*2B = 71.3 MB
    __bf16* ctx = xh;

    split_kernel<<<dim3(8192), 256, 0, stream>>>(x, Wq, Wk, Wv, Wo,
                                                 xh, xl, wqh, wql, wkh, wkl, wvh, woh);
    qkv_kernel<<<dim3(24, 32), 256, 0, stream>>>(xh, xl, wqh, wql, wkh, wkl, wvh,
                                                 bq, bk, bv, qh, ql, kh, kl, vt);
    attn_kernel<<<dim3(512), 512, 0, stream>>>(qh, ql, kh, kl, vt, attn, ctx);
    out_kernel<<<dim3(16, 32), 256, 0, stream>>>(ctx, woh, bo, out);
}

// Round 7
// 712.910 us; speedup vs baseline: 1.1978x; 1.1978x over previous
//
#include <hip/hip_runtime.h>
#include <hip/hip_bf16.h>

// Problem: B=2, S=2048, HID=1024, NH=16, HD=64. fp32 in/out (per reference).
// d_out = [out (2*2048*1024) | attn (2*16*2048*2048)] fp32.
// NOTE: requires ws_size >= 71.3 MB (7*NQ + 6*NW bf16 elems).
#define BB   2
#define SS   2048
#define HID  1024
#define NH   16
#define HD   64
#define NEGS -30000.0f

typedef __bf16 bf16x8 __attribute__((ext_vector_type(8)));
typedef __bf16 bf16x4 __attribute__((ext_vector_type(4)));
typedef float  f32x4  __attribute__((ext_vector_type(4)));

static __device__ __forceinline__ f32x4 mfma_bf16(bf16x8 a, bf16x8 b, f32x4 c) {
    return __builtin_amdgcn_mfma_f32_16x16x32_bf16(a, b, c, 0, 0, 0);
}

static __device__ __forceinline__ void split_bf16(float f, __bf16* hp, __bf16* lp) {
    __bf16 h = (__bf16)f;
    *hp = h;
    *lp = (__bf16)(f - (float)h);
}

static __device__ __forceinline__ float clampf(float v, float lo, float hi) {
    return fminf(fmaxf(v, lo), hi);   // also scrubs NaN -> lo
}

// async global->LDS, 16B per lane; dest must be wave-uniform base (+ lane*16 by HW)
static __device__ __forceinline__ void gll16(const __bf16* g, __bf16* l) {
    __builtin_amdgcn_global_load_lds((const void*)g, (void*)l, 16, 0, 0);
}

// barrier that drains only LDS counters (keeps global_load_lds prefetch in flight)
static __device__ __forceinline__ void barrier_lds() {
    asm volatile("s_waitcnt lgkmcnt(0)" ::: "memory");
    __builtin_amdgcn_sched_barrier(0);
    __builtin_amdgcn_s_barrier();
    __builtin_amdgcn_sched_barrier(0);
}

// barrier that waits staged gll tiles but NOT the trailing attn stores:
// per-wave vmem issue order in pass B is [3x gll][4x store], so vmcnt(4)
// guarantees the glls retired while stores may stay in flight.
static __device__ __forceinline__ void barrier_vm4() {
    asm volatile("s_waitcnt vmcnt(4) lgkmcnt(0)" ::: "memory");
    __builtin_amdgcn_sched_barrier(0);
    __builtin_amdgcn_s_barrier();
    __builtin_amdgcn_sched_barrier(0);
}
static __device__ __forceinline__ void barrier_vm0() {
    asm volatile("s_waitcnt vmcnt(0) lgkmcnt(0)" ::: "memory");
    __builtin_amdgcn_sched_barrier(0);
    __builtin_amdgcn_s_barrier();
    __builtin_amdgcn_sched_barrier(0);
}

// ---------------------------------------------------------------------------
// K0: one-time hi/lo bf16 pre-split of x and the weights. Tight 1D grid.
// Wq is pre-scaled by 8 (exact: power-of-2), so qkv folds the score scale.
// ---------------------------------------------------------------------------
__global__ __launch_bounds__(256) void split_kernel(
    const float* __restrict__ x,
    const float* __restrict__ Wq, const float* __restrict__ Wk,
    const float* __restrict__ Wv, const float* __restrict__ Wo,
    __bf16* __restrict__ xh, __bf16* __restrict__ xl,
    __bf16* __restrict__ wqh, __bf16* __restrict__ wql,
    __bf16* __restrict__ wkh, __bf16* __restrict__ wkl,
    __bf16* __restrict__ wvh, __bf16* __restrict__ woh)
{
    const int bid = blockIdx.x;
    if (bid < 4096) {                      // x: 4096*256*4 == BB*SS*HID exactly
        const int i4 = bid * 256 + threadIdx.x;
        const float4 v = ((const float4*)x)[i4];
        const float* p = (const float*)&v;
        bf16x4 h4, l4v;
#pragma unroll
        for (int j = 0; j < 4; j++) { __bf16 hh, ll; split_bf16(p[j], &hh, &ll); h4[j] = hh; l4v[j] = ll; }
        *(bf16x4*)&xh[(size_t)i4 * 4] = h4;
        *(bf16x4*)&xl[(size_t)i4 * 4] = l4v;
        return;
    }
    const int wb = bid - 4096;             // 4 x 1024 blocks, 1024*256*4 == HID*HID
    const int which = (wb >> 10) + 1;
    const int i4 = (wb & 1023) * 256 + threadIdx.x;
    const float* src = which == 1 ? Wq : which == 2 ? Wk : which == 3 ? Wv : Wo;
    const float sc = (which == 1) ? 8.0f : 1.0f;
    const float4 v = ((const float4*)src)[i4];
    const float* p = (const float*)&v;
    bf16x4 h4, l4v;
#pragma unroll
    for (int j = 0; j < 4; j++) { __bf16 hh, ll; split_bf16(p[j] * sc, &hh, &ll); h4[j] = hh; l4v[j] = ll; }
    if (which == 1)      { *(bf16x4*)&wqh[(size_t)i4 * 4] = h4; *(bf16x4*)&wql[(size_t)i4 * 4] = l4v; }
    else if (which == 2) { *(bf16x4*)&wkh[(size_t)i4 * 4] = h4; *(bf16x4*)&wkl[(size_t)i4 * 4] = l4v; }
    else if (which == 3) { *(bf16x4*)&wvh[(size_t)i4 * 4] = h4; }
    else                 { *(bf16x4*)&woh[(size_t)i4 * 4] = h4; }
}

// ---------------------------------------------------------------------------
// K1: QKV projection, 128x128 tile, BK=32, gll staging, double-buffered LDS.
// Q/K: 3-chain MFMA (hi*hi + hi*lo + lo*hi), V: hi-only.  (v5, measured 724)
// ---------------------------------------------------------------------------
__global__ __launch_bounds__(256) void qkv_kernel(
    const __bf16* __restrict__ xh, const __bf16* __restrict__ xl,
    const __bf16* __restrict__ wqh, const __bf16* __restrict__ wql,
    const __bf16* __restrict__ wkh, const __bf16* __restrict__ wkl,
    const __bf16* __restrict__ wvh,
    const float* __restrict__ bq, const float* __restrict__ bk, const float* __restrict__ bv,
    __bf16* __restrict__ qh, __bf16* __restrict__ ql,
    __bf16* __restrict__ kh, __bf16* __restrict__ kl,
    __bf16* __restrict__ vt)
{
    // buffer set b at smem + b*16384: Ah=+0, Al=+4096, Bh=+8192, Bl=+12288
    __shared__ __align__(16) __bf16 smem[32768];   // 64KB -> 2 blocks/CU

    const int stream = blockIdx.x >> 3, ct = blockIdx.x & 7;
    const int t0 = blockIdx.y * 128, c0 = ct * 128;
    const bool qk = stream < 2;
    const __bf16* const Bhg = stream == 0 ? wqh : stream == 1 ? wkh : wvh;
    const __bf16* const Blg = stream == 0 ? wql : wkl;     // unused for V
    const float* const bias = stream == 0 ? bq : stream == 1 ? bk : bv;
    const float bscale = stream == 0 ? 8.0f : 1.0f;        // Wq pre-scaled: scale bias too

    const int tid = threadIdx.x, wave = tid >> 6, lane = tid & 63;
    const int l16 = lane & 15, quad = lane >> 4;
    const int wr = wave >> 1, wc = wave & 1;

    // staging map: 4 16B slots/row, slot-XOR swizzle by (row&3) on BOTH sides
    const int ar0 = tid >> 2,         as0 = (tid & 3) ^ (ar0 & 3);
    const int ar1 = (256 + tid) >> 2, as1 = ((256 + tid) & 3) ^ (ar1 & 3);
    const size_t aoff0 = (size_t)(t0 + ar0) * HID + as0 * 8;
    const size_t aoff1 = (size_t)(t0 + ar1) * HID + as1 * 8;
    const size_t boff0 = (size_t)(c0 + ar0) * HID + as0 * 8;
    const size_t boff1 = (size_t)(c0 + ar1) * HID + as1 * 8;
    const int ld0 = wave << 9, ld1 = (4 + wave) << 9;      // 1KB chunks per wave

#define QKV_STAGE(b_, k0_) do {                                   \
        __bf16* s_ = smem + (b_) * 16384;                         \
        gll16(xh + aoff0 + (k0_), s_ + ld0);                      \
        gll16(xh + aoff1 + (k0_), s_ + ld1);                      \
        gll16(Bhg + boff0 + (k0_), s_ + 8192 + ld0);              \
        gll16(Bhg + boff1 + (k0_), s_ + 8192 + ld1);              \
        if (qk) {                                                 \
            gll16(xl + aoff0 + (k0_), s_ + 4096 + ld0);           \
            gll16(xl + aoff1 + (k0_), s_ + 4096 + ld1);           \
            gll16(Blg + boff0 + (k0_), s_ + 12288 + ld0);         \
            gll16(Blg + boff1 + (k0_), s_ + 12288 + ld1);         \
        }                                                         \
    } while (0)

    const f32x4 zero4 = {0.f, 0.f, 0.f, 0.f};
    f32x4 acc[4][4];
#pragma unroll
    for (int i = 0; i < 4; i++)
#pragma unroll
        for (int j = 0; j < 4; j++) acc[i][j] = zero4;

    QKV_STAGE(0, 0);
    for (int k0 = 0; k0 < HID; k0 += 32) {
        const int cur = (k0 >> 5) & 1;
        __syncthreads();                 // buf[cur] landed; prev readers of buf[cur^1] done
        if (k0 + 32 < HID) QKV_STAGE(cur ^ 1, k0 + 32);
        __bf16* const s_ = smem + cur * 16384;

        bf16x8 aH[4], aL[4], bHf[4], bLf[4];
#pragma unroll
        for (int mf = 0; mf < 4; mf++) {
            const int row = wr * 64 + mf * 16 + l16;
            const int off = row * 32 + ((quad ^ (row & 3)) << 3);
            aH[mf] = *(const bf16x8*)(s_ + off);
            if (qk) aL[mf] = *(const bf16x8*)(s_ + 4096 + off);
        }
#pragma unroll
        for (int nf = 0; nf < 4; nf++) {
            const int row = wc * 64 + nf * 16 + l16;
            const int off = row * 32 + ((quad ^ (row & 3)) << 3);
            bHf[nf] = *(const bf16x8*)(s_ + 8192 + off);
            if (qk) bLf[nf] = *(const bf16x8*)(s_ + 12288 + off);
        }
#pragma unroll
        for (int mf = 0; mf < 4; mf++)
#pragma unroll
            for (int nf = 0; nf < 4; nf++) {
                acc[mf][nf] = mfma_bf16(aH[mf], bHf[nf], acc[mf][nf]);
                if (qk) {
                    acc[mf][nf] = mfma_bf16(aH[mf], bLf[nf], acc[mf][nf]);
                    acc[mf][nf] = mfma_bf16(aL[mf], bHf[nf], acc[mf][nf]);
                }
            }
    }
#undef QKV_STAGE

    const int bidx = t0 >> 11;           // batch (tile never crosses batch boundary)
    const int s0 = t0 & (SS - 1);

    if (qk) {
        // epilogue via LDS: [128][132] bf16, coalesced uint4 stores, hi then lo
        __bf16* const Es = smem;
        __bf16* const hi_arr = stream == 0 ? qh : kh;
        __bf16* const lo_arr = stream == 0 ? ql : kl;
#pragma unroll
        for (int pass = 0; pass < 2; pass++) {
            __syncthreads();             // prior smem readers (frags / pass-0 stores) done
#pragma unroll
            for (int nf = 0; nf < 4; nf++) {
                const int dcl = wc * 64 + nf * 16 + l16;
                const float bv_ = bias[c0 + dcl] * bscale;
#pragma unroll
                for (int mf = 0; mf < 4; mf++)
#pragma unroll
                    for (int r = 0; r < 4; r++) {
                        const int srl = wr * 64 + mf * 16 + quad * 4 + r;
                        const float v = clampf(acc[mf][nf][r] + bv_, -1e4f, 1e4f);
                        __bf16 hv, lv;
                        split_bf16(v, &hv, &lv);
                        Es[srl * 132 + dcl] = pass ? lv : hv;
                    }
            }
            __syncthreads();
            __bf16* const dst = pass ? lo_arr : hi_arr;
#pragma unroll
            for (int i = 0; i < 8; i++) {
                const int idx = tid + i * 256;           // 2048 16B chunks
                const int row = idx >> 4, c16 = idx & 15;
                const int hh = (c0 >> 6) + (c16 >> 3);
                const int dd = (c16 & 7) * 8;
                const size_t o = ((size_t)(bidx * NH + hh) * SS + (s0 + row)) * HD + dd;
                *(uint4*)&dst[o] = *(const uint4*)&Es[row * 132 + c16 * 8];
            }
        }
    } else {
        // V: each wave transposes its own 64x64 subtile through its own LDS region
        __syncthreads();                            // all frag reads of smem done
        __bf16* const Vts = smem + wave * 4608;     // [64][72]
#pragma unroll
        for (int nf = 0; nf < 4; nf++) {
            const int dloc = nf * 16 + l16;
            const float bv_ = bias[c0 + wc * 64 + dloc];
#pragma unroll
            for (int mf = 0; mf < 4; mf++)
#pragma unroll
                for (int r = 0; r < 4; r++)
                    Vts[dloc * 72 + mf * 16 + quad * 4 + r] =
                        (__bf16)clampf(acc[mf][nf][r] + bv_, -1e4f, 1e4f);
        }
        const int hh = (c0 + wc * 64) >> 6;
        const size_t vb = (size_t)(bidx * NH + hh) * HD * SS;
        const int sc0 = s0 + wr * 64;
#pragma unroll
        for (int j = 0; j < 8; j++) {               // same-wave readback: no barrier needed
            const int idx = j * 64 + lane;
            const int d = idx >> 3, c8 = idx & 7;
            *(uint4*)&vt[vb + (size_t)d * SS + sc0 + c8 * 8] =
                *(const uint4*)&Vts[d * 72 + c8 * 8];
        }
    }
}

// ---------------------------------------------------------------------------
// K2: causal attention, two-pass online softmax.  (v5 structure, measured 724)
// 512 blocks (one 128-row q-tile each), 2 blocks/CU (66KB LDS, VGPR<=128 via
// launch_bounds(512,4)) -> one block's pass-A MFMA overlaps the other's pass-B
// HBM writes. Pass-B top barrier uses counted vmcnt(4). Only v7 change:
// zero-fill stores are nontemporal (268MB never re-read; spare the L2).
// ---------------------------------------------------------------------------
__global__ __launch_bounds__(512, 4) void attn_kernel(
    const __bf16* __restrict__ qh, const __bf16* __restrict__ ql,
    const __bf16* __restrict__ kh, const __bf16* __restrict__ kl,
    const __bf16* __restrict__ vt,
    float* __restrict__ attn, __bf16* __restrict__ ctx)
{
    __shared__ __align__(16) __bf16 Kh0[4096], Kl0[4096], Kh1[4096], Kl1[4096];
    __shared__ __align__(16) __bf16 Vt0[4096], Vt1[4096];
    __shared__ __align__(16) __bf16 Ps[128][72];      // 66KB total

    const int bid  = blockIdx.x;           // [0,512)
    const int half = bid >> 8;             // 0: heavy qt 15..8, 1: light qt 0..7
    const int ii   = bid & 255;
    const int g    = ii & 7;               // XCD (round-robin)
    const int bh   = g + 8 * ((ii >> 3) & 3);   // 4 bh per XCD
    const int p    = ii >> 5;              // [0,8)
    const int qt   = half ? p : (15 - p);
    const int nj   = 2 * qt + 2;
    const int b    = bh >> 4, h = bh & 15;

    const int tid  = threadIdx.x;
    const int wave = tid >> 6, lane = tid & 63;
    const int l16  = lane & 15, quad = lane >> 4;

    // gll staging map (512 thr: one call covers a 64x128B tile)
    const int sr = tid >> 3, ssw = (tid & 7) ^ (sr & 7);
    const size_t kq = (size_t)sr * HD + ssw * 8;
    const size_t vq = (size_t)sr * SS + ssw * 8;
    const int ldw = wave << 9;

    const __bf16* const khp = kh + (size_t)bh * SS * HD;
    const __bf16* const klp = kl + (size_t)bh * SS * HD;
    const __bf16* const vtp = vt + (size_t)bh * HD * SS;

#define STAGE_K(j_, KH, KL) do {                                  \
        const __bf16* kg_ = khp + (size_t)(j_) * (64 * HD);       \
        const __bf16* lg_ = klp + (size_t)(j_) * (64 * HD);       \
        gll16(kg_ + kq, (KH) + ldw); gll16(lg_ + kq, (KL) + ldw); \
    } while (0)
#define STAGE_V(j_, VT) do {                                      \
        const __bf16* vg_ = vtp + (size_t)(j_) * 64;              \
        gll16(vg_ + vq, (VT) + ldw);                              \
    } while (0)

    const f32x4 zero4 = {0.f, 0.f, 0.f, 0.f};

    // Q fragments straight to registers (128B-row coalesced loads)
    bf16x8 aHq[2], aLq[2];
    {
        const size_t qrow = ((size_t)bh * SS + qt * 128 + wave * 16 + l16) * HD;
#pragma unroll
        for (int ks = 0; ks < 2; ks++) {
            aHq[ks] = *(const bf16x8*)&qh[qrow + ks * 32 + quad * 8];
            aLq[ks] = *(const bf16x8*)&ql[qrow + ks * 32 + quad * 8];
        }
    }

    float m4[4], l4[4];
#pragma unroll
    for (int r = 0; r < 4; r++) { m4[r] = NEGS; l4[r] = 0.f; }

    STAGE_K(0, Kh0, Kl0);
    __syncthreads();                        // K0 landed

    // ---- pass A: per-lane online max/sumexp ----
    for (int j = 0; j < nj; j++) {
        if (j) __syncthreads();             // buf[j&1] ready (drains prefetch)
        if (j < nj - 1) {
            if (j & 1) STAGE_K(j + 1, Kh0, Kl0);
            else       STAGE_K(j + 1, Kh1, Kl1);
        }
        const __bf16* const Khc = (j & 1) ? Kh1 : Kh0;
        const __bf16* const Klc = (j & 1) ? Kl1 : Kl0;

        f32x4 sacc[4] = {zero4, zero4, zero4, zero4};
#pragma unroll
        for (int ks = 0; ks < 2; ks++)
#pragma unroll
            for (int c = 0; c < 4; c++) {
                const int krow = c * 16 + l16;
                const int ko = krow * 64 + (((ks * 4 + quad) ^ (krow & 7)) << 3);
                const bf16x8 bH = *(const bf16x8*)(Khc + ko);
                const bf16x8 bL = *(const bf16x8*)(Klc + ko);
                sacc[c] = mfma_bf16(aHq[ks], bH, sacc[c]);
                sacc[c] = mfma_bf16(aHq[ks], bL, sacc[c]);
                sacc[c] = mfma_bf16(aLq[ks], bH, sacc[c]);
            }
        if (j >= 2 * qt) {
            const int cb = j * 64, qr = qt * 128 + wave * 16 + quad * 4;
#pragma unroll
            for (int c = 0; c < 4; c++) {
                const int col = cb + c * 16 + l16;
#pragma unroll
                for (int r = 0; r < 4; r++)
                    if (col > qr + r) sacc[c][r] = NEGS;
            }
        }
#pragma unroll
        for (int r = 0; r < 4; r++) {       // lane-local online update
            const float mx = fmaxf(fmaxf(sacc[0][r], sacc[1][r]),
                                   fmaxf(sacc[2][r], sacc[3][r]));
            const float mn = fmaxf(m4[r], mx);
            l4[r] = l4[r] * __expf(m4[r] - mn)
                  + __expf(sacc[0][r] - mn) + __expf(sacc[1][r] - mn)
                  + __expf(sacc[2][r] - mn) + __expf(sacc[3][r] - mn);
            m4[r] = mn;
        }
    }

    // single cross-lane merge over 16-lane column groups
    float il[4];
#pragma unroll
    for (int r = 0; r < 4; r++) {
#pragma unroll
        for (int off = 1; off < 16; off <<= 1) {
            const float mo  = __shfl_xor(m4[r], off);
            const float lo_ = __shfl_xor(l4[r], off);
            const float mn  = fmaxf(m4[r], mo);
            l4[r] = l4[r] * __expf(m4[r] - mn) + lo_ * __expf(mo - mn);
            m4[r] = mn;
        }
        il[r] = (l4[r] > 0.f) ? (1.0f / l4[r]) : 0.f;
    }

    f32x4 cacc[4] = {zero4, zero4, zero4, zero4};

    __syncthreads();                        // pass-A buffer reads finished everywhere
    STAGE_K(0, Kh0, Kl0);
    STAGE_V(0, Vt0);

    // ---- pass B: attn write (fp32) + ctx accumulate ----
    for (int j = 0; j < nj; j++) {
        if (j == 0) barrier_vm0();          // initial tile landed
        else        barrier_vm4();          // staged tile landed; store acks in flight
        if (j < nj - 1) {
            if (j & 1) { STAGE_K(j + 1, Kh0, Kl0); STAGE_V(j + 1, Vt0); }
            else       { STAGE_K(j + 1, Kh1, Kl1); STAGE_V(j + 1, Vt1); }
        }
        const __bf16* const Khc = (j & 1) ? Kh1 : Kh0;
        const __bf16* const Klc = (j & 1) ? Kl1 : Kl0;
        const __bf16* const Vtc = (j & 1) ? Vt1 : Vt0;

        f32x4 sacc[4] = {zero4, zero4, zero4, zero4};
#pragma unroll
        for (int ks = 0; ks < 2; ks++)
#pragma unroll
            for (int c = 0; c < 4; c++) {
                const int krow = c * 16 + l16;
                const int ko = krow * 64 + (((ks * 4 + quad) ^ (krow & 7)) << 3);
                const bf16x8 bH = *(const bf16x8*)(Khc + ko);
                const bf16x8 bL = *(const bf16x8*)(Klc + ko);
                sacc[c] = mfma_bf16(aHq[ks], bH, sacc[c]);
                sacc[c] = mfma_bf16(aHq[ks], bL, sacc[c]);
                sacc[c] = mfma_bf16(aLq[ks], bH, sacc[c]);
            }
        if (j >= 2 * qt) {
            const int cb = j * 64, qr = qt * 128 + wave * 16 + quad * 4;
#pragma unroll
            for (int c = 0; c < 4; c++) {
                const int col = cb + c * 16 + l16;
#pragma unroll
                for (int r = 0; r < 4; r++)
                    if (col > qr + r) sacc[c][r] = NEGS;
            }
        }
#pragma unroll
        for (int c = 0; c < 4; c++)
#pragma unroll
            for (int r = 0; r < 4; r++) {
                const float pv = clampf(__expf(sacc[c][r] - m4[r]) * il[r], 0.f, 1.f);
                Ps[wave * 16 + quad * 4 + r][c * 16 + l16] = (__bf16)pv;
            }
        barrier_lds();                      // Ps visible; gll prefetch NOT drained

        // coalesced fp32 attn store (upconvert the same bf16 P used for P·V)
#pragma unroll
        for (int i = 0; i < 2; i++) {
            const int idx = tid + i * 512;
            const int row = idx >> 3, c8 = idx & 7;
            const size_t o = ((size_t)bh * SS + qt * 128 + row) * SS + j * 64 + c8 * 8;
            __bf16 tmp[8];
            *(uint4*)tmp = *(const uint4*)&Ps[row][c8 * 8];
            float4 f0, f1;
            f0.x = (float)tmp[0]; f0.y = (float)tmp[1];
            f0.z = (float)tmp[2]; f0.w = (float)tmp[3];
            f1.x = (float)tmp[4]; f1.y = (float)tmp[5];
            f1.z = (float)tmp[6]; f1.w = (float)tmp[7];
            *(float4*)&attn[o]     = f0;
            *(float4*)&attn[o + 4] = f1;
        }
        // ctx += P @ V
#pragma unroll
        for (int ks = 0; ks < 2; ks++) {
            const bf16x8 ap = *(const bf16x8*)&Ps[wave * 16 + l16][ks * 32 + quad * 8];
#pragma unroll
            for (int dt = 0; dt < 4; dt++) {
                const int vrow = dt * 16 + l16;
                const int vo = vrow * 64 + (((ks * 4 + quad) ^ (vrow & 7)) << 3);
                cacc[dt] = mfma_bf16(ap, *(const bf16x8*)(Vtc + vo), cacc[dt]);
            }
        }
    }

    // zero-fill upper-triangle tiles (fp32, nontemporal: never re-read)
    const f32x4 zf4 = {0.f, 0.f, 0.f, 0.f};
    for (int j = nj; j < SS / 64; j++) {
#pragma unroll
        for (int i = 0; i < 4; i++) {
            const int idx = tid + i * 512;          // [0,2048)
            const int row = idx >> 4, c4 = idx & 15;
            const size_t o = ((size_t)bh * SS + qt * 128 + row) * SS + j * 64 + c4 * 4;
            __builtin_nontemporal_store(zf4, (f32x4*)&attn[o]);
        }
    }

    // ctx epilogue via Ps: coalesced bf16 stores
    __syncthreads();                        // all Ps readers (attn store/PV) done
#pragma unroll
    for (int dt = 0; dt < 4; dt++) {
        const int d = dt * 16 + l16;
#pragma unroll
        for (int r = 0; r < 4; r++)
            Ps[wave * 16 + quad * 4 + r][d] =
                (__bf16)clampf(cacc[dt][r], -1e4f, 1e4f);
    }
    __syncthreads();
#pragma unroll
    for (int i = 0; i < 2; i++) {
        const int idx = tid + i * 512;              // 1024 chunks = 128 rows x 8
        const int row = idx >> 3, c8 = idx & 7;
        *(uint4*)&ctx[(size_t)(b * SS + qt * 128 + row) * HID + h * 64 + c8 * 8] =
            *(const uint4*)&Ps[row][c8 * 8];
    }
#undef STAGE_K
#undef STAGE_V
}

// ---------------------------------------------------------------------------
// K3: out = ctx @ Wo^T + bo   (ctx bf16, woh pre-split bf16-hi)
// v5: 128x64 tile (M x N), grid (16,32) = 512 blocks -> 2 blocks/CU,
// double-buffered LDS (24KB), one barrier per K-step.
// ---------------------------------------------------------------------------
__global__ __launch_bounds__(256) void out_kernel(
    const __bf16* __restrict__ ctx, const __bf16* __restrict__ woh,
    const float* __restrict__ bo, float* __restrict__ out)
{
    // buffer set b at smem + b*6144: As(128x32)=+0, Bs(64x32)=+4096
    __shared__ __align__(16) __bf16 smem[12288];   // 24KB

    const int o0 = blockIdx.x * 64;      // N-tile (output cols)
    const int t0 = blockIdx.y * 128;     // M-tile (rows)

    const int tid = threadIdx.x, wave = tid >> 6, lane = tid & 63;
    const int l16 = lane & 15, quad = lane >> 4;
    const int wr = wave >> 1, wc = wave & 1;   // 2x2 wave grid: 64 rows x 32 cols each

    // A staging: 128 rows, 2 glls/wave; B staging: 64 rows, 1 gll/wave
    const int ar0 = tid >> 2,         as0 = (tid & 3) ^ (ar0 & 3);
    const int ar1 = (256 + tid) >> 2, as1 = ((256 + tid) & 3) ^ (ar1 & 3);
    const size_t aoff0 = (size_t)(t0 + ar0) * HID + as0 * 8;
    const size_t aoff1 = (size_t)(t0 + ar1) * HID + as1 * 8;
    const size_t boff  = (size_t)(o0 + ar0) * HID + as0 * 8;   // ar0<64 covered by tid<256
    const int ld0 = wave << 9, ld1 = (4 + wave) << 9;

#define OUT_STAGE(b_, k0_) do {                                   \
        __bf16* s_ = smem + (b_) * 6144;                          \
        gll16(ctx + aoff0 + (k0_), s_ + ld0);                     \
        gll16(ctx + aoff1 + (k0_), s_ + ld1);                     \
        gll16(woh + boff + (k0_), s_ + 4096 + ld0);               \
    } while (0)

    const f32x4 zero4 = {0.f, 0.f, 0.f, 0.f};
    f32x4 acc[4][2];
#pragma unroll
    for (int i = 0; i < 4; i++)
#pragma unroll
        for (int j = 0; j < 2; j++) acc[i][j] = zero4;

    OUT_STAGE(0, 0);
    for (int k0 = 0; k0 < HID; k0 += 32) {
        const int cur = (k0 >> 5) & 1;
        __syncthreads();                 // buf[cur] landed; prev readers of buf[cur^1] done
        if (k0 + 32 < HID) OUT_STAGE(cur ^ 1, k0 + 32);
        __bf16* const s_ = smem + cur * 6144;

        bf16x8 aH[4], bHf[2];
#pragma unroll
        for (int mf = 0; mf < 4; mf++) {
            const int row = wr * 64 + mf * 16 + l16;
            aH[mf] = *(const bf16x8*)(s_ + row * 32 + ((quad ^ (row & 3)) << 3));
        }
#pragma unroll
        for (int nf = 0; nf < 2; nf++) {
            const int row = wc * 32 + nf * 16 + l16;
            bHf[nf] = *(const bf16x8*)(s_ + 4096 + row * 32 + ((quad ^ (row & 3)) << 3));
        }
#pragma unroll
        for (int mf = 0; mf < 4; mf++)
#pragma unroll
            for (int nf = 0; nf < 2; nf++)
                acc[mf][nf] = mfma_bf16(aH[mf], bHf[nf], acc[mf][nf]);
    }
#undef OUT_STAGE

#pragma unroll
    for (int nf = 0; nf < 2; nf++) {
        const int dcol = o0 + wc * 32 + nf * 16 + l16;
        const float bias = bo[dcol];
#pragma unroll
        for (int mf = 0; mf < 4; mf++)
#pragma unroll
            for (int r = 0; r < 4; r++) {
                const int t = t0 + wr * 64 + mf * 16 + quad * 4 + r;
                out[(size_t)t * HID + dcol] = clampf(acc[mf][nf][r] + bias, -1e4f, 1e4f);
            }
    }
}

extern "C" void kernel_launch(void* const* d_in, const int* in_sizes, int n_in,
                              void* d_out, int out_size, void* d_ws, size_t ws_size,
                              hipStream_t stream) {
    const float* x  = (const float*)d_in[0];
    const float* Wq = (const float*)d_in[1];
    const float* bq = (const float*)d_in[2];
    const float* Wk = (const float*)d_in[3];
    const float* bk = (const float*)d_in[4];
    const float* Wv = (const float*)d_in[5];
    const float* bv = (const float*)d_in[6];
    const float* Wo = (const float*)d_in[7];
    const float* bo = (const float*)d_in[8];

    float* out  = (float*)d_out;
    float* attn = out + (size_t)BB * SS * HID;

    const size_t NQ = (size_t)BB * NH * SS * HD;   // 4,194,304
    const size_t NW = (size_t)HID * HID;           // 1,048,576
    __bf16* ws  = (__bf16*)d_ws;
    __bf16* qh  = ws;
    __bf16* ql  = ws + NQ;
    __bf16* kh  = ws + 2 * NQ;
    __bf16* kl  = ws + 3 * NQ;
    __bf16* vt  = ws + 4 * NQ;
    __bf16* xh  = ws + 5 * NQ;     // dead after qkv -> reused as ctx
    __bf16* xl  = ws + 6 * NQ;
    __bf16* wqh = ws + 7 * NQ;
    __bf16* wql = wqh + NW;
    __bf16* wkh = wqh + 2 * NW;
    __bf16* wkl = wqh + 3 * NW;
    __bf16* wvh = wqh + 4 * NW;
    __bf16* woh = wqh + 5 * NW;    // total (7*NQ + 6*NW)*2B = 71.3 MB
    __bf16* ctx = xh;

    split_kernel<<<dim3(8192), 256, 0, stream>>>(x, Wq, Wk, Wv, Wo,
                                                 xh, xl, wqh, wql, wkh, wkl, wvh, woh);
    qkv_kernel<<<dim3(24, 32), 256, 0, stream>>>(xh, xl, wqh, wql, wkh, wkl, wvh,
                                                 bq, bk, bv, qh, ql, kh, kl, vt);
    attn_kernel<<<dim3(512), 512, 0, stream>>>(qh, ql, kh, kl, vt, attn, ctx);
    out_kernel<<<dim3(16, 32), 256, 0, stream>>>(ctx, woh, bo, out);
}